// Round 9
// baseline (421.213 us; speedup 1.0000x reference)
//
#include <hip/hip_runtime.h>

typedef unsigned int u32;
typedef _Float16 f16;
typedef f16 h2 __attribute__((ext_vector_type(2)));
typedef __attribute__((ext_vector_type(8)))  _Float16 f16x8;
typedef __attribute__((ext_vector_type(16))) float    f32x16;

// ---------------- packed-weight ws layout (u32/f32 element offsets) ----------
#define QP     0        // legacy (unused by k_main now)
#define KVP    256
#define WOP    768
#define ILWP   1024     // legacy scalar enc weights (unused by k_main now)
#define WIHP   9216     // [(kp<16 *32 + t)*4 + j] j<3 used         (2048)
#define WHHP   11264    //                                          (2048)
#define MSWP   13312    // [kp<16 *32 + t]                          (512)
#define MGWP   13824    // [a*512 + kp<16 *32 + m]                  (32768)
#define QSWP   46592    // [kp<32 *32 + t]                          (1024)
#define AHWP   47616    // [a*256 + kp<16 *16 + u]                  (16384)
#define F32B   64000
#define BQ     (F32B+0)     // 32
#define BKV    (F32B+32)    // 64
#define BO     (F32B+96)    // 16
#define LN1G   (F32B+112)   // 16
#define LN1B   (F32B+128)   // 16
#define ILB    (F32B+144)   // 32
#define BIH    (F32B+176)   // 96
#define BHH    (F32B+272)   // 96
#define MSB    (F32B+368)   // 32
#define MGB    (F32B+400)   // 2048
#define MAWKVV (F32B+2448)  // 1024  wkv_V as [k<32][t<32]
#define MABKVV (F32B+3472)  // 32
#define MAWO   (F32B+3504)  // 1024
#define MABO   (F32B+4528)  // 32
#define LN2G   (F32B+4560)  // 32
#define LN2B   (F32B+4592)  // 32
#define QSB    (F32B+4624)  // 32
#define AHB    (F32B+4656)  // 1024
#define W_TOTAL (F32B+5680) // 69680
// ---- MFMA fragment regions ----
// slot convention sigma(hf,j6): j6<4 -> 4*hf+j6 ; j6>=4 -> 8+4*hf+(j6-4).
// Dlay32 (C/D, HW-verified): row(reg r, half hf) = (r&3)+8*(r>>2)+4*hf, col=lane&31.
#define QTA    69680    // A-frag of (CS/2)*Wq^T  [64 lanes][4 u32]
#define KTA    69936    // A-frag of Wk^T
#define WVB    70192    // B-frag of Wv
#define WOTA   70448    // 2 A-frags of Wo^T (K-split f<16 / f>=16), rows g>=16 zero
#define BQT    70960    // f32 [hf][16 regs] = (CS/2)*bq[row(r,hf)]
#define BKT    70992    // f32 bk[row]
#define BOT    71024    // f32 bo[row<16] else 0
#define ILWA   71056    // il_w^T A-frags for coop enc MFMA: [step<32][lane][4 u32]
#define W_TOTAL3 79248
#define W_ALLOC  79296

// output element offsets (f32): q_values | h | mean_message
#define OUT_Q  0
#define OUT_H  1048576
#define OUT_MM 3145728

// softmax scale in exp2 domain; /2 because scores duplicate each head-feat
// twice across the K=16 slots: CS2 = 0.5 * (1/sqrt(8)) * log2(e)
#define CS2 (0.5f * 0.35355339059327373f * 1.4426950408889634f)

#if __has_builtin(__builtin_amdgcn_wave_barrier)
#define WB() __builtin_amdgcn_wave_barrier()
#else
#define WB() __threadfence_block()
#endif

#if __has_builtin(__builtin_amdgcn_exp2f)
__device__ __forceinline__ float EXP2(float x) { return __builtin_amdgcn_exp2f(x); }
#else
__device__ __forceinline__ float EXP2(float x) { return __expf(x * 0.6931471805599453f); }
#endif

#if __has_builtin(__builtin_amdgcn_fdot2)
__device__ __forceinline__ float FD(h2 a, h2 b, float c) {
    return __builtin_amdgcn_fdot2(a, b, c, false);
}
#else
__device__ __forceinline__ float FD(h2 a, h2 b, float c) {
    return c + (float)a.x * (float)b.x + (float)a.y * (float)b.y;
}
#endif

#if __has_builtin(__builtin_amdgcn_cvt_pkrtz)
__device__ __forceinline__ h2 pk2(float a, float b) {
    auto r = __builtin_amdgcn_cvt_pkrtz(a, b);
    h2 out;
    __builtin_memcpy(&out, &r, sizeof(out));
    return out;
}
#else
__device__ __forceinline__ h2 pk2(float a, float b) { h2 r; r.x = (f16)a; r.y = (f16)b; return r; }
#endif

__device__ __forceinline__ h2  u2h(u32 x) { union { u32 u; h2 h; } c; c.u = x; return c.h; }
__device__ __forceinline__ u32 h2u(h2 x)  { union { u32 u; h2 h; } c; c.h = x; return c.u; }
__device__ __forceinline__ f16x8 mk8(u32 a, u32 b, u32 c, u32 d) {
    union { u32 u[4]; f16x8 v; } x; x.u[0]=a; x.u[1]=b; x.u[2]=c; x.u[3]=d; return x.v;
}
#define MFMA32(a,b,c) __builtin_amdgcn_mfma_f32_32x32x16_f16(a, b, c, 0, 0, 0)

__device__ __forceinline__ float sigm(float x) { return 1.0f / (1.0f + __expf(-x)); }

struct WP { const float* p[30]; };

// K0: repack weights: f16 pairs + f32 tail + MFMA fragments
__global__ void kw_conv(WP wp, float* W) {
    u32* Wu = (u32*)W;
    int gid = blockIdx.x * blockDim.x + threadIdx.x;
    if (gid >= W_TOTAL3) return;
    if (gid < KVP) {                       // legacy QP
        int e = gid >> 3, i = gid & 7;
        const float* wq = wp.p[0];
        Wu[gid] = h2u(pk2(wq[(2*i)*32 + e], wq[(2*i+1)*32 + e]));
    } else if (gid < WOP) {                // legacy KVP
        int idx = gid - KVP; int e = idx >> 3, i = idx & 7;
        const float* wkv = wp.p[2];
        Wu[gid] = h2u(pk2(wkv[(2*i)*64 + e], wkv[(2*i+1)*64 + e]));
    } else if (gid < ILWP) {               // legacy WOP
        int idx = gid - WOP; int f = idx >> 4, i = idx & 15;
        const float* wo = wp.p[4];
        Wu[gid] = h2u(pk2(wo[(2*i)*16 + f], wo[(2*i+1)*16 + f]));
    } else if (gid < WIHP) {               // legacy ILWP (unused; kept for layout)
        int idx = gid - ILWP;
        int jp4 = idx >> 7, t = (idx >> 2) & 31, i = idx & 3;
        int jp = jp4 * 4 + i;
        const float* ilw = wp.p[8];
        Wu[gid] = h2u(pk2(ilw[(2*jp)*32 + t], ilw[(2*jp+1)*32 + t]));
    } else if (gid < WHHP) {               // WIHP: gru_wih [32][96]
        int idx = gid - WIHP;
        int kp = idx >> 7, t = (idx >> 2) & 31, j = idx & 3;
        const float* wih = wp.p[10];
        Wu[gid] = (j < 3) ? h2u(pk2(wih[(2*kp)*96 + j*32 + t], wih[(2*kp+1)*96 + j*32 + t])) : 0u;
    } else if (gid < MSWP) {               // WHHP: gru_whh [32][96]
        int idx = gid - WHHP;
        int kp = idx >> 7, t = (idx >> 2) & 31, j = idx & 3;
        const float* whh = wp.p[11];
        Wu[gid] = (j < 3) ? h2u(pk2(whh[(2*kp)*96 + j*32 + t], whh[(2*kp+1)*96 + j*32 + t])) : 0u;
    } else if (gid < MGWP) {               // MSWP: ms_w [32][32]
        int idx = gid - MSWP; int kp = idx >> 5, t = idx & 31;
        const float* msw = wp.p[14];
        Wu[gid] = h2u(pk2(msw[(2*kp)*32 + t], msw[(2*kp+1)*32 + t]));
    } else if (gid < QSWP) {               // MGWP: mg_w [64][32][32]
        int idx = gid - MGWP; int a = idx >> 9, rem = idx & 511, kp = rem >> 5, m = rem & 31;
        const float* mgw = wp.p[16];
        Wu[gid] = h2u(pk2(mgw[(a*32 + 2*kp)*32 + m], mgw[(a*32 + 2*kp+1)*32 + m]));
    } else if (gid < AHWP) {               // QSWP: qs_w [64][32]
        int idx = gid - QSWP; int kp = idx >> 5, t = idx & 31;
        const float* qsw = wp.p[26];
        Wu[gid] = h2u(pk2(qsw[(2*kp)*32 + t], qsw[(2*kp+1)*32 + t]));
    } else if (gid < F32B) {               // AHWP: ah_w [64][32][16]
        int idx = gid - AHWP; int a = idx >> 8, rem = idx & 255, kp = rem >> 4, u = rem & 15;
        const float* ahw = wp.p[28];
        Wu[gid] = h2u(pk2(ahw[(a*32 + 2*kp)*16 + u], ahw[(a*32 + 2*kp+1)*16 + u]));
    } else if (gid < W_TOTAL) {            // f32 tail
        int i = gid - F32B;
        float v;
        if      (i < 32)   v = wp.p[1][i];                 // bq (raw; CS2 fold in BQT)
        else if (i < 96)   v = wp.p[3][i - 32];            // bkv
        else if (i < 112)  v = wp.p[5][i - 96];            // bo
        else if (i < 128)  v = wp.p[6][i - 112];           // ln1_g
        else if (i < 144)  v = wp.p[7][i - 128];           // ln1_b
        else if (i < 176)  v = wp.p[9][i - 144];           // il_b
        else if (i < 272)  v = wp.p[12][i - 176];          // gru_bih
        else if (i < 368)  v = wp.p[13][i - 272];          // gru_bhh
        else if (i < 400)  v = wp.p[15][i - 368];          // ms_b
        else if (i < 2448) v = wp.p[17][i - 400];          // mg_b
        else if (i < 3472) { int j = i - 2448; v = wp.p[20][(j >> 5)*64 + 32 + (j & 31)]; } // ma_wkv V
        else if (i < 3504) v = wp.p[21][32 + (i - 3472)];  // ma_bkv V
        else if (i < 4528) v = wp.p[22][i - 3504];         // ma_wo
        else if (i < 4560) v = wp.p[23][i - 4528];         // ma_bo
        else if (i < 4592) v = wp.p[24][i - 4560];         // ln2_g
        else if (i < 4624) v = wp.p[25][i - 4592];         // ln2_b
        else if (i < 4656) v = wp.p[27][i - 4624];         // qs_b
        else               v = wp.p[29][i - 4656];         // ah_b
        W[gid] = v;
    } else if (gid < KTA) {                // QTA: (CS/2)*Wq^T A-frag
        int idx = gid - QTA; int l = idx >> 2, j = idx & 3;
        int g = l & 31, hf = l >> 5;
        int k0 = (j < 2) ? (4*hf + 2*j) : (8 + 4*hf + 2*(j-2));
        const float* wq = wp.p[0];
        Wu[gid] = h2u(pk2(wq[k0*32 + g] * CS2, wq[(k0+1)*32 + g] * CS2));
    } else if (gid < WVB) {                // KTA: Wk^T A-frag (wkv cols 0..31)
        int idx = gid - KTA; int l = idx >> 2, j = idx & 3;
        int g = l & 31, hf = l >> 5;
        int k0 = (j < 2) ? (4*hf + 2*j) : (8 + 4*hf + 2*(j-2));
        const float* wkv = wp.p[2];
        Wu[gid] = h2u(pk2(wkv[k0*64 + g], wkv[(k0+1)*64 + g]));
    } else if (gid < WOTA) {               // WVB: Wv B-frag (wkv cols 32..63)
        int idx = gid - WVB; int l = idx >> 2, j = idx & 3;
        int n = l & 31, hf = l >> 5;
        int k0 = (j < 2) ? (4*hf + 2*j) : (8 + 4*hf + 2*(j-2));
        const float* wkv = wp.p[2];
        Wu[gid] = h2u(pk2(wkv[k0*64 + 32 + n], wkv[(k0+1)*64 + 32 + n]));
    } else if (gid < BQT) {                // WOTA: Wo^T A-frags (2 K-halves)
        int idx = gid - WOTA; int kh = idx >> 8, rem = idx & 255;
        int l = rem >> 2, j = rem & 3;
        int g = l & 31, hf = l >> 5;
        int f0 = kh*16 + ((j < 2) ? (4*hf + 2*j) : (8 + 4*hf + 2*(j-2)));
        const float* wo = wp.p[4];
        Wu[gid] = (g < 16) ? h2u(pk2(wo[f0*16 + g], wo[(f0+1)*16 + g])) : 0u;
    } else if (gid < ILWA) {               // BQT/BKT/BOT f32, Dlay-ordered
        int i = gid - BQT;
        int hf = (i >> 4) & 1, r = i & 15;
        int row = (r & 3) + 8*(r >> 2) + 4*hf;
        float v;
        if      (i < 32) v = wp.p[1][row] * CS2;           // bq * CS/2
        else if (i < 64) v = wp.p[3][row];                 // bk
        else             v = (row < 16) ? wp.p[5][row] : 0.0f;  // bo
        W[gid] = v;
    } else {                               // ILWA: il_w^T A-frags (enc MFMA)
        int idx = gid - ILWA; int s = idx >> 8, rem = idx & 255;
        int l = rem >> 2, j = rem & 3;
        int g = l & 31, hf = l >> 5;
        int k0 = s*16 + ((j < 2) ? (4*hf + 2*j) : (8 + 4*hf + 2*(j-2)));
        const float* ilw = wp.p[8];
        Wu[gid] = h2u(pk2(ilw[k0*32 + g], ilw[(k0+1)*32 + g]));
    }
}

// K1 (MFMA P0-P4): r8-verified structure. r9 deltas:
//  - aftL rows padded 256 -> 260 u32 (260%32=4): coop-enc B-frag reads hit 8
//    DISTINCT banks across the 8 agent rows (was: 256%32=0 -> all rows bank 0,
//    8-way conflict, 16.25M SQ_LDS_BANK_CONFLICT/dispatch). Duplicated lanes
//    (lane>=8 within a half) are same-address broadcasts (free). Pair reads
//    stay 8B-aligned (1040-byte row stride) so b64 merging survives.
//  - launch_bounds (256,4): VGPR now 80 (r8) < 128 cap -> no spill risk (r6's
//    spill was ~160 live under 128); 16 waves/CU vs 12 for latency hiding.
//    WATCH: WRITE_SIZE >> 16MB => cap spilled, revert to (,3).
__global__ __launch_bounds__(256, 4) void k_main(
    const float* __restrict__ states, const float* __restrict__ hidden,
    const float* W, float* __restrict__ outp)
{
    const u32* Wu = (const u32*)W;

    __shared__ __align__(16) u32   aftL[8][260];     // padded: bank-spread agent rows
    __shared__ __align__(16) float encPartS[4][32][9]; // padded: no 8-way bank conflict
    __shared__ __align__(16) float encS[8][32];
    __shared__ __align__(16) float hnS[8][32];
    __shared__ __align__(16) float membS[8][32];

    const int w    = threadIdx.x >> 6;
    const int lane = threadIdx.x & 63;
    const int sub  = lane >> 5;
    const int t    = lane & 31;      // link row / matrix col
    const int hf   = sub;            // mfma half id
    const int pair = blockIdx.x * 4 + w;
    const int b    = pair >> 5;
    const int a    = ((pair & 31) << 1) | sub;   // tail agent (half-wave)
    const int ba   = b * 64 + a;
    const int ag   = w * 2 + sub;

    float hp = hidden[(size_t)ba * 32 + t];

    // wave-uniform-per-lane weight fragments (QKV)
    f16x8 wqa = mk8(Wu[QTA + lane*4+0], Wu[QTA + lane*4+1], Wu[QTA + lane*4+2], Wu[QTA + lane*4+3]);
    f16x8 wka = mk8(Wu[KTA + lane*4+0], Wu[KTA + lane*4+1], Wu[KTA + lane*4+2], Wu[KTA + lane*4+3]);
    f16x8 wvb = mk8(Wu[WVB + lane*4+0], Wu[WVB + lane*4+1], Wu[WVB + lane*4+2], Wu[WVB + lane*4+3]);
    float bv  = W[BKV + 32 + t];     // V bias per feat = per lane col

    for (int ap = 0; ap < 2; ++ap) {
        const int ag2 = w * 2 + ap;
        const int baA = b * 64 + (((pair & 31) << 1) | ap);
        const float* sp = states + (size_t)baA * 512;
        // S-frag: lane = link t, slots sigma(hf,j) = feats {4hf..+3, 8+4hf..+3}
        float4 f0 = *reinterpret_cast<const float4*>(sp + t*16 + 4*hf);
        float4 f1 = *reinterpret_cast<const float4*>(sp + t*16 + 8 + 4*hf);
        float sv[8] = {f0.x,f0.y,f0.z,f0.w, f1.x,f1.y,f1.z,f1.w};
        f16x8 sf = mk8(h2u(pk2(f0.x,f0.y)), h2u(pk2(f0.z,f0.w)),
                       h2u(pk2(f1.x,f1.y)), h2u(pk2(f1.z,f1.w)));

        // QKV projections (pack each result immediately -> short live ranges)
        f32x16 cc;
        #pragma unroll
        for (int r = 0; r < 16; ++r) cc[r] = W[BQT + hf*16 + r];
        u32 qp[8], kp[8];
        {
            f32x16 dq = MFMA32(wqa, sf, cc);   // Q^T: rows=feat, cols=link
            #pragma unroll
            for (int h = 0; h < 4; ++h) {
                qp[2*h]   = h2u(pk2(dq[4*h],   dq[4*h+1]));
                qp[2*h+1] = h2u(pk2(dq[4*h+2], dq[4*h+3]));
            }
        }
        #pragma unroll
        for (int r = 0; r < 16; ++r) cc[r] = W[BKT + hf*16 + r];
        {
            f32x16 dk = MFMA32(wka, sf, cc);   // K^T
            #pragma unroll
            for (int h = 0; h < 4; ++h) {
                kp[2*h]   = h2u(pk2(dk[4*h],   dk[4*h+1]));
                kp[2*h+1] = h2u(pk2(dk[4*h+2], dk[4*h+3]));
            }
        }
        #pragma unroll
        for (int r = 0; r < 16; ++r) cc[r] = bv;
        f16x8 vaf, vbf;
        {
            f32x16 dv = MFMA32(sf, wvb, cc);   // V: rows=link, cols=feat(lane)
            vaf = mk8(h2u(pk2(dv[0],dv[1])),  h2u(pk2(dv[2],dv[3])),
                      h2u(pk2(dv[4],dv[5])),  h2u(pk2(dv[6],dv[7])));
            vbf = mk8(h2u(pk2(dv[8],dv[9])),  h2u(pk2(dv[10],dv[11])),
                      h2u(pk2(dv[12],dv[13])),h2u(pk2(dv[14],dv[15])));
        }

        f32x16 zro;
        #pragma unroll
        for (int r = 0; r < 16; ++r) zro[r] = 0.0f;

        // per-head attention with out-proj folded in per head-pair
        f32x16 da;
        #pragma unroll
        for (int r = 0; r < 16; ++r) da[r] = W[BOT + hf*16 + r];
        u32 op[4];
        #pragma unroll
        for (int h = 0; h < 4; ++h) {
            // duplicated-head-feat frags (slots j and j+4 carry same feats)
            f16x8 ak = mk8(kp[2*h], kp[2*h+1], kp[2*h], kp[2*h+1]);
            f16x8 bq = mk8(qp[2*h], qp[2*h+1], qp[2*h], qp[2*h+1]);
            f32x16 ds = MFMA32(ak, bq, zro);         // CS-scaled S^T (exp2 dom)
            f32x16 p;
            float ls = 0.0f;
            #pragma unroll
            for (int r = 0; r < 16; ++r) { p[r] = EXP2(ds[r]); ls += p[r]; }
            ls += __shfl_xor(ls, 32, 64);            // full 32-kl row sum
            float inv = 1.0f / ls;                   // deferred to extraction
            f16x8 paf = mk8(h2u(pk2(p[0], p[1])),  h2u(pk2(p[2], p[3])),
                            h2u(pk2(p[4], p[5])),  h2u(pk2(p[6], p[7])));
            f16x8 pbf = mk8(h2u(pk2(p[8], p[9])),  h2u(pk2(p[10],p[11])),
                            h2u(pk2(p[12],p[13])), h2u(pk2(p[14],p[15])));
            f32x16 dt = MFMA32(vaf, paf, zro);
            dt = MFMA32(vbf, pbf, dt);               // O^T_h (unnorm): rows=feat
            // extract valid rows (own regs 4h..4h+3), normalize per lane col q
            op[2*(h&1)]   = h2u(pk2(dt[4*h]*inv,   dt[4*h+1]*inv));
            op[2*(h&1)+1] = h2u(pk2(dt[4*h+2]*inv, dt[4*h+3]*inv));
            if (h & 1) {                             // pair complete -> out-proj
                const int kh = h >> 1;
                f16x8 woh = mk8(Wu[WOTA + kh*256 + lane*4+0], Wu[WOTA + kh*256 + lane*4+1],
                                Wu[WOTA + kh*256 + lane*4+2], Wu[WOTA + kh*256 + lane*4+3]);
                da = MFMA32(woh, mk8(op[0],op[1],op[2],op[3]), da);
            }
        }

        // residual + LN over 16 feats; own regs 0..7 <-> sv feats exactly
        float x[8];
        float sm = 0.0f;
        #pragma unroll
        for (int r = 0; r < 8; ++r) { x[r] = da[r] + sv[r]; sm += x[r]; }
        sm += __shfl_xor(sm, 32, 64);
        float mean = sm * (1.0f / 16.0f);
        float vv = 0.0f;
        #pragma unroll
        for (int r = 0; r < 8; ++r) { float d = x[r] - mean; vv += d * d; }
        vv += __shfl_xor(vv, 32, 64);
        float rs = rsqrtf(vv * (1.0f / 16.0f) + 1e-5f);
        float4 g0 = *reinterpret_cast<const float4*>(W + LN1G + 4*hf);
        float4 g1 = *reinterpret_cast<const float4*>(W + LN1G + 8 + 4*hf);
        float4 e0 = *reinterpret_cast<const float4*>(W + LN1B + 4*hf);
        float4 e1 = *reinterpret_cast<const float4*>(W + LN1B + 8 + 4*hf);
        float gam[8] = {g0.x,g0.y,g0.z,g0.w, g1.x,g1.y,g1.z,g1.w};
        float bet[8] = {e0.x,e0.y,e0.z,e0.w, e1.x,e1.y,e1.z,e1.w};
        float af[8];
        #pragma unroll
        for (int r = 0; r < 8; ++r) af[r] = (x[r] - mean) * rs * gam[r] + bet[r];
        // aft -> LDS flat pair index (link*16+feat)/2 (f16 pairs)
        int i0 = t * 8 + 2 * hf;
        aftL[ag2][i0]     = h2u(pk2(af[0], af[1]));
        aftL[ag2][i0 + 1] = h2u(pk2(af[2], af[3]));
        aftL[ag2][i0 + 4] = h2u(pk2(af[4], af[5]));
        aftL[ag2][i0 + 5] = h2u(pk2(af[6], af[7]));
    }
    __syncthreads();   // all 8 agents' aftL visible block-wide

    // ---- P4 (coop MFMA): enc^T[t][agent] = il_w^T . aft, K split across waves.
    // A = il_w^T frags (ILWA, sigma-packed); B = aft pairs (cols 0..7 = agents,
    // cols 8..31 duplicate agent lane&7 -> broadcast reads, results ignored).
    {
        f32x16 de;
        #pragma unroll
        for (int r = 0; r < 16; ++r) de[r] = 0.0f;
        const int cb = lane & 7;
        #pragma unroll
        for (int ss = 0; ss < 8; ++ss) {
            const int s = w * 8 + ss;    // this wave's K-step (link s)
            uint4 av = *reinterpret_cast<const uint4*>(Wu + ILWA + s*256 + lane*4);
            f16x8 ae = mk8(av.x, av.y, av.z, av.w);
            const u32* ap8 = &aftL[cb][s * 8];
            f16x8 be = mk8(ap8[2*hf], ap8[2*hf + 1], ap8[4 + 2*hf], ap8[5 + 2*hf]);
            de = MFMA32(ae, be, de);     // accumulate over K-steps
        }
        const int c = lane & 31;
        if (c < 8) {
            #pragma unroll
            for (int r = 0; r < 16; ++r)
                encPartS[w][(r & 3) + 8*(r >> 2) + 4*hf][c] = de[r];
        }
    }
    __syncthreads();   // partials from all 4 waves visible
    {
        float enc = W[ILB + t] + encPartS[0][t][ag] + encPartS[1][t][ag]
                  + encPartS[2][t][ag] + encPartS[3][t][ag];
        WB();
        encS[ag][t] = enc;
        WB();
    }

    // ---- P5: GRU ----
    float gi0 = W[BIH + t], gi1 = W[BIH + 32 + t], gi2 = W[BIH + 64 + t];
    float gh0 = W[BHH + t], gh1 = W[BHH + 32 + t], gh2 = W[BHH + 64 + t];
    {
        const float4* eF = (const float4*)&encS[ag][0];
        const float4* hF = (const float4*)(hidden + (size_t)ba * 32);
        const uint4* wi4 = (const uint4*)(Wu + WIHP);
        const uint4* wh4 = (const uint4*)(Wu + WHHP);
        #pragma unroll
        for (int q4 = 0; q4 < 8; ++q4) {
            float4 ev = eF[q4], hv = hF[q4];
            h2 ea = pk2(ev.x, ev.y), eb = pk2(ev.z, ev.w);
            h2 ha = pk2(hv.x, hv.y), hb = pk2(hv.z, hv.w);
            uint4 wiA = wi4[(q4*2)*32 + t], wiB = wi4[(q4*2+1)*32 + t];
            uint4 whA = wh4[(q4*2)*32 + t], whB = wh4[(q4*2+1)*32 + t];
            gi0 = FD(ea, u2h(wiA.x), gi0); gi1 = FD(ea, u2h(wiA.y), gi1); gi2 = FD(ea, u2h(wiA.z), gi2);
            gi0 = FD(eb, u2h(wiB.x), gi0); gi1 = FD(eb, u2h(wiB.y), gi1); gi2 = FD(eb, u2h(wiB.z), gi2);
            gh0 = FD(ha, u2h(whA.x), gh0); gh1 = FD(ha, u2h(whA.y), gh1); gh2 = FD(ha, u2h(whA.z), gh2);
            gh0 = FD(hb, u2h(whB.x), gh0); gh1 = FD(hb, u2h(whB.y), gh1); gh2 = FD(hb, u2h(whB.z), gh2);
        }
    }
    float r  = sigm(gi0 + gh0);
    float z  = sigm(gi1 + gh1);
    float n  = tanhf(gi2 + r * gh2);
    float hn = (1.0f - z) * n + z * hp;
    outp[OUT_H + (size_t)ba * 32 + t] = hn;
    WB();
    hnS[ag][t] = hn;
    WB();

    // ---- P6: memb = relu(h @ ms_w + b); msg = memb @ mg_w[a] + b ----
    {
        const float4* nF = (const float4*)&hnS[ag][0];
        float mb = W[MSB + t];
        #pragma unroll
        for (int q4 = 0; q4 < 8; ++q4) {
            float4 v = nF[q4];
            h2 a2 = pk2(v.x, v.y), b2 = pk2(v.z, v.w);
            mb = FD(a2, u2h(Wu[MSWP + (q4*2)*32 + t]), mb);
            mb = FD(b2, u2h(Wu[MSWP + (q4*2+1)*32 + t]), mb);
        }
        mb = fmaxf(mb, 0.0f);
        WB();
        membS[ag][t] = mb;
        WB();
    }
    {
        const float4* mF = (const float4*)&membS[ag][0];
        float mg = W[MGB + a * 32 + t];
        #pragma unroll
        for (int q4 = 0; q4 < 8; ++q4) {
            float4 v = mF[q4];
            h2 a2 = pk2(v.x, v.y), b2 = pk2(v.z, v.w);
            mg = FD(a2, u2h(Wu[MGWP + a*512 + (q4*2)*32 + t]), mg);
            mg = FD(b2, u2h(Wu[MGWP + a*512 + (q4*2+1)*32 + t]), mg);
        }
        outp[OUT_MM + (size_t)ba * 32 + t] = mg;
    }
}

// K2: per-batch message mean + degenerate comm-attn (unchanged, r5 passing)
__global__ __launch_bounds__(512) void k_mean(const float* W, float* __restrict__ ao_ws,
                                              float* __restrict__ outp)
{
    const int b   = blockIdx.x;
    const int tid = threadIdx.x;
    const int t   = tid & 31;
    const int c   = tid >> 5;        // 0..15
    __shared__ float pS[16][32];
    __shared__ float mmS[32];

    float acc = 0.0f;
    #pragma unroll
    for (int a2 = 0; a2 < 4; ++a2)
        acc += outp[OUT_MM + ((size_t)b * 64 + (a2 * 16 + c)) * 32 + t];
    pS[c][t] = acc;
    __syncthreads();
    if (tid < 32) {
        float ssum = 0.0f;
        #pragma unroll
        for (int cc = 0; cc < 16; ++cc) ssum += pS[cc][t];
        mmS[t] = ssum * (1.0f / 64.0f);
    }
    __syncthreads();
    {
        float mv = mmS[t];
        #pragma unroll
        for (int i = 0; i < 4; ++i)
            outp[OUT_MM + (size_t)b * 2048 + i * 512 + tid] = mv;
    }
    if (tid < 32) {
        float v = W[MABKVV + t];
        #pragma unroll 8
        for (int k = 0; k < 32; ++k) v += mmS[k] * W[MAWKVV + k * 32 + t];
        float o = W[MABO + t];
        #pragma unroll 8
        for (int k = 0; k < 32; ++k) o += __shfl(v, k, 64) * W[MAWO + k * 32 + t];
        ao_ws[b * 32 + t] = o;
    }
}

// K3: LN2(h + ao[b]) -> feat=[h,after] -> relu(qs) -> per-agent Q head
// (unchanged, r5 passing)
__global__ __launch_bounds__(512) void k_tail(
    const float* __restrict__ ao_ws, const float* W, float* __restrict__ outp)
{
    const u32* Wu = (const u32*)W;
    __shared__ __align__(16) float featS[16][64];
    __shared__ __align__(16) float qeS[16][32];
    const int w    = threadIdx.x >> 6;
    const int lane = threadIdx.x & 63;
    const int sub  = lane >> 5;
    const int t    = lane & 31;
    const int ag   = w * 2 + sub;
    const int pair = blockIdx.x * 8 + w;
    const int b    = pair >> 5;
    const int a    = ((pair & 31) << 1) | sub;
    const int ba   = b * 64 + a;

    float h  = outp[OUT_H + (size_t)ba * 32 + t];
    float ao = ao_ws[b * 32 + t];
    float x  = h + ao;
    float sm = x;
    #pragma unroll
    for (int m2 = 1; m2 < 32; m2 <<= 1) sm += __shfl_xor(sm, m2, 64);
    float mean = sm * (1.0f / 32.0f);
    float dx = x - mean;
    float vv = dx * dx;
    #pragma unroll
    for (int m2 = 1; m2 < 32; m2 <<= 1) vv += __shfl_xor(vv, m2, 64);
    float var   = vv * (1.0f / 32.0f);
    float after = dx * rsqrtf(var + 1e-5f) * W[LN2G + t] + W[LN2B + t];

    featS[ag][t]      = h;
    featS[ag][32 + t] = after;
    WB();
    {
        const float4* fF = (const float4*)&featS[ag][0];
        float acc = W[QSB + t];
        #pragma unroll
        for (int q4 = 0; q4 < 16; ++q4) {
            float4 v = fF[q4];
            h2 a2 = pk2(v.x, v.y), b2 = pk2(v.z, v.w);
            acc = FD(a2, u2h(Wu[QSWP + (q4*2)*32 + t]), acc);
            acc = FD(b2, u2h(Wu[QSWP + (q4*2+1)*32 + t]), acc);
        }
        acc = fmaxf(acc, 0.0f);
        WB();
        qeS[ag][t] = acc;
        WB();
    }
    if (t < 16) {
        const float4* qF = (const float4*)&qeS[ag][0];
        float qa = W[AHB + a * 16 + t];
        #pragma unroll
        for (int q4 = 0; q4 < 8; ++q4) {
            float4 v = qF[q4];
            h2 a2 = pk2(v.x, v.y), b2 = pk2(v.z, v.w);
            qa = FD(a2, u2h(Wu[AHWP + a*256 + (q4*2)*16 + t]), qa);
            qa = FD(b2, u2h(Wu[AHWP + a*256 + (q4*2+1)*16 + t]), qa);
        }
        outp[OUT_Q + (size_t)ba * 16 + t] = qa;
    }
}

extern "C" void kernel_launch(void* const* d_in, const int* in_sizes, int n_in,
                              void* d_out, int out_size, void* d_ws, size_t ws_size,
                              hipStream_t stream) {
    (void)in_sizes; (void)n_in; (void)out_size; (void)ws_size;
    WP wp;
    for (int i = 0; i < 30; ++i) wp.p[i] = (const float*)d_in[i + 2];

    float* W     = (float*)d_ws;
    float* ao_ws = W + W_ALLOC;   // 1024*32 f32

    const float* states = (const float*)d_in[0];
    const float* hidden = (const float*)d_in[1];
    float* outp = (float*)d_out;

    kw_conv<<<dim3((W_TOTAL3 + 255) / 256), dim3(256), 0, stream>>>(wp, W);
    k_main<<<dim3(8192), dim3(256), 0, stream>>>(states, hidden, W, outp);
    k_mean<<<dim3(1024), dim3(512), 0, stream>>>(W, ao_ws, outp);
    k_tail<<<dim3(4096), dim3(512), 0, stream>>>(ao_ws, W, outp);
}

// Round 10
// 378.753 us; speedup vs baseline: 1.1121x; 1.1121x over previous
//
#include <hip/hip_runtime.h>

typedef unsigned int u32;
typedef _Float16 f16;
typedef f16 h2 __attribute__((ext_vector_type(2)));
typedef __attribute__((ext_vector_type(8)))  _Float16 f16x8;
typedef __attribute__((ext_vector_type(16))) float    f32x16;

// ---------------- packed-weight ws layout (u32/f32 element offsets) ----------
#define QP     0        // legacy (unused by k_main now)
#define KVP    256
#define WOP    768
#define ILWP   1024     // legacy scalar enc weights (unused by k_main now)
#define WIHP   9216     // [(kp<16 *32 + t)*4 + j] j<3 used         (2048)
#define WHHP   11264    //                                          (2048)
#define MSWP   13312    // [kp<16 *32 + t]                          (512)
#define MGWP   13824    // [a*512 + kp<16 *32 + m]                  (32768)
#define QSWP   46592    // [kp<32 *32 + t]                          (1024)
#define AHWP   47616    // [a*256 + kp<16 *16 + u]                  (16384)
#define F32B   64000
#define BQ     (F32B+0)     // 32
#define BKV    (F32B+32)    // 64
#define BO     (F32B+96)    // 16
#define LN1G   (F32B+112)   // 16
#define LN1B   (F32B+128)   // 16
#define ILB    (F32B+144)   // 32
#define BIH    (F32B+176)   // 96
#define BHH    (F32B+272)   // 96
#define MSB    (F32B+368)   // 32
#define MGB    (F32B+400)   // 2048
#define MAWKVV (F32B+2448)  // 1024  wkv_V as [k<32][t<32]
#define MABKVV (F32B+3472)  // 32
#define MAWO   (F32B+3504)  // 1024
#define MABO   (F32B+4528)  // 32
#define LN2G   (F32B+4560)  // 32
#define LN2B   (F32B+4592)  // 32
#define QSB    (F32B+4624)  // 32
#define AHB    (F32B+4656)  // 1024
#define W_TOTAL (F32B+5680) // 69680
// ---- MFMA fragment regions ----
// slot convention sigma(hf,j6): j6<4 -> 4*hf+j6 ; j6>=4 -> 8+4*hf+(j6-4).
// Dlay32 (C/D, HW-verified): row(reg r, half hf) = (r&3)+8*(r>>2)+4*hf, col=lane&31.
#define QTA    69680    // A-frag of (CS/2)*Wq^T  [64 lanes][4 u32]
#define KTA    69936    // A-frag of Wk^T
#define WVB    70192    // B-frag of Wv
#define WOTA   70448    // 2 A-frags of Wo^T (K-split f<16 / f>=16), rows g>=16 zero
#define BQT    70960    // f32 [hf][16 regs] = (CS/2)*bq[row(r,hf)]
#define BKT    70992    // f32 bk[row]
#define BOT    71024    // f32 bo[row<16] else 0
#define ILWA   71056    // il_w^T A-frags for coop enc MFMA: [step<32][lane][4 u32]
#define W_TOTAL3 79248
#define W_ALLOC  79296

// output element offsets (f32): q_values | h | mean_message
#define OUT_Q  0
#define OUT_H  1048576
#define OUT_MM 3145728

// softmax scale in exp2 domain; /2 because scores duplicate each head-feat
// twice across the K=16 slots: CS2 = 0.5 * (1/sqrt(8)) * log2(e)
#define CS2 (0.5f * 0.35355339059327373f * 1.4426950408889634f)

#if __has_builtin(__builtin_amdgcn_wave_barrier)
#define WB() __builtin_amdgcn_wave_barrier()
#else
#define WB() __threadfence_block()
#endif

#if __has_builtin(__builtin_amdgcn_exp2f)
__device__ __forceinline__ float EXP2(float x) { return __builtin_amdgcn_exp2f(x); }
#else
__device__ __forceinline__ float EXP2(float x) { return __expf(x * 0.6931471805599453f); }
#endif

#if __has_builtin(__builtin_amdgcn_fdot2)
__device__ __forceinline__ float FD(h2 a, h2 b, float c) {
    return __builtin_amdgcn_fdot2(a, b, c, false);
}
#else
__device__ __forceinline__ float FD(h2 a, h2 b, float c) {
    return c + (float)a.x * (float)b.x + (float)a.y * (float)b.y;
}
#endif

#if __has_builtin(__builtin_amdgcn_cvt_pkrtz)
__device__ __forceinline__ h2 pk2(float a, float b) {
    auto r = __builtin_amdgcn_cvt_pkrtz(a, b);
    h2 out;
    __builtin_memcpy(&out, &r, sizeof(out));
    return out;
}
#else
__device__ __forceinline__ h2 pk2(float a, float b) { h2 r; r.x = (f16)a; r.y = (f16)b; return r; }
#endif

__device__ __forceinline__ h2  u2h(u32 x) { union { u32 u; h2 h; } c; c.u = x; return c.h; }
__device__ __forceinline__ u32 h2u(h2 x)  { union { u32 u; h2 h; } c; c.h = x; return c.u; }
__device__ __forceinline__ f16x8 mk8(u32 a, u32 b, u32 c, u32 d) {
    union { u32 u[4]; f16x8 v; } x; x.u[0]=a; x.u[1]=b; x.u[2]=c; x.u[3]=d; return x.v;
}
#define MFMA32(a,b,c) __builtin_amdgcn_mfma_f32_32x32x16_f16(a, b, c, 0, 0, 0)

__device__ __forceinline__ float sigm(float x) { return 1.0f / (1.0f + __expf(-x)); }

struct WP { const float* p[30]; };

// K0: repack weights: f16 pairs + f32 tail + MFMA fragments
__global__ void kw_conv(WP wp, float* W) {
    u32* Wu = (u32*)W;
    int gid = blockIdx.x * blockDim.x + threadIdx.x;
    if (gid >= W_TOTAL3) return;
    if (gid < KVP) {                       // legacy QP
        int e = gid >> 3, i = gid & 7;
        const float* wq = wp.p[0];
        Wu[gid] = h2u(pk2(wq[(2*i)*32 + e], wq[(2*i+1)*32 + e]));
    } else if (gid < WOP) {                // legacy KVP
        int idx = gid - KVP; int e = idx >> 3, i = idx & 7;
        const float* wkv = wp.p[2];
        Wu[gid] = h2u(pk2(wkv[(2*i)*64 + e], wkv[(2*i+1)*64 + e]));
    } else if (gid < ILWP) {               // legacy WOP
        int idx = gid - WOP; int f = idx >> 4, i = idx & 15;
        const float* wo = wp.p[4];
        Wu[gid] = h2u(pk2(wo[(2*i)*16 + f], wo[(2*i+1)*16 + f]));
    } else if (gid < WIHP) {               // legacy ILWP (unused; kept for layout)
        int idx = gid - ILWP;
        int jp4 = idx >> 7, t = (idx >> 2) & 31, i = idx & 3;
        int jp = jp4 * 4 + i;
        const float* ilw = wp.p[8];
        Wu[gid] = h2u(pk2(ilw[(2*jp)*32 + t], ilw[(2*jp+1)*32 + t]));
    } else if (gid < WHHP) {               // WIHP: gru_wih [32][96]
        int idx = gid - WIHP;
        int kp = idx >> 7, t = (idx >> 2) & 31, j = idx & 3;
        const float* wih = wp.p[10];
        Wu[gid] = (j < 3) ? h2u(pk2(wih[(2*kp)*96 + j*32 + t], wih[(2*kp+1)*96 + j*32 + t])) : 0u;
    } else if (gid < MSWP) {               // WHHP: gru_whh [32][96]
        int idx = gid - WHHP;
        int kp = idx >> 7, t = (idx >> 2) & 31, j = idx & 3;
        const float* whh = wp.p[11];
        Wu[gid] = (j < 3) ? h2u(pk2(whh[(2*kp)*96 + j*32 + t], whh[(2*kp+1)*96 + j*32 + t])) : 0u;
    } else if (gid < MGWP) {               // MSWP: ms_w [32][32]
        int idx = gid - MSWP; int kp = idx >> 5, t = idx & 31;
        const float* msw = wp.p[14];
        Wu[gid] = h2u(pk2(msw[(2*kp)*32 + t], msw[(2*kp+1)*32 + t]));
    } else if (gid < QSWP) {               // MGWP: mg_w [64][32][32]
        int idx = gid - MGWP; int a = idx >> 9, rem = idx & 511, kp = rem >> 5, m = rem & 31;
        const float* mgw = wp.p[16];
        Wu[gid] = h2u(pk2(mgw[(a*32 + 2*kp)*32 + m], mgw[(a*32 + 2*kp+1)*32 + m]));
    } else if (gid < AHWP) {               // QSWP: qs_w [64][32]
        int idx = gid - QSWP; int kp = idx >> 5, t = idx & 31;
        const float* qsw = wp.p[26];
        Wu[gid] = h2u(pk2(qsw[(2*kp)*32 + t], qsw[(2*kp+1)*32 + t]));
    } else if (gid < F32B) {               // AHWP: ah_w [64][32][16]
        int idx = gid - AHWP; int a = idx >> 8, rem = idx & 255, kp = rem >> 4, u = rem & 15;
        const float* ahw = wp.p[28];
        Wu[gid] = h2u(pk2(ahw[(a*32 + 2*kp)*16 + u], ahw[(a*32 + 2*kp+1)*16 + u]));
    } else if (gid < W_TOTAL) {            // f32 tail
        int i = gid - F32B;
        float v;
        if      (i < 32)   v = wp.p[1][i];                 // bq (raw; CS2 fold in BQT)
        else if (i < 96)   v = wp.p[3][i - 32];            // bkv
        else if (i < 112)  v = wp.p[5][i - 96];            // bo
        else if (i < 128)  v = wp.p[6][i - 112];           // ln1_g
        else if (i < 144)  v = wp.p[7][i - 128];           // ln1_b
        else if (i < 176)  v = wp.p[9][i - 144];           // il_b
        else if (i < 272)  v = wp.p[12][i - 176];          // gru_bih
        else if (i < 368)  v = wp.p[13][i - 272];          // gru_bhh
        else if (i < 400)  v = wp.p[15][i - 368];          // ms_b
        else if (i < 2448) v = wp.p[17][i - 400];          // mg_b
        else if (i < 3472) { int j = i - 2448; v = wp.p[20][(j >> 5)*64 + 32 + (j & 31)]; } // ma_wkv V
        else if (i < 3504) v = wp.p[21][32 + (i - 3472)];  // ma_bkv V
        else if (i < 4528) v = wp.p[22][i - 3504];         // ma_wo
        else if (i < 4560) v = wp.p[23][i - 4528];         // ma_bo
        else if (i < 4592) v = wp.p[24][i - 4560];         // ln2_g
        else if (i < 4624) v = wp.p[25][i - 4592];         // ln2_b
        else if (i < 4656) v = wp.p[27][i - 4624];         // qs_b
        else               v = wp.p[29][i - 4656];         // ah_b
        W[gid] = v;
    } else if (gid < KTA) {                // QTA: (CS/2)*Wq^T A-frag
        int idx = gid - QTA; int l = idx >> 2, j = idx & 3;
        int g = l & 31, hf = l >> 5;
        int k0 = (j < 2) ? (4*hf + 2*j) : (8 + 4*hf + 2*(j-2));
        const float* wq = wp.p[0];
        Wu[gid] = h2u(pk2(wq[k0*32 + g] * CS2, wq[(k0+1)*32 + g] * CS2));
    } else if (gid < WVB) {                // KTA: Wk^T A-frag (wkv cols 0..31)
        int idx = gid - KTA; int l = idx >> 2, j = idx & 3;
        int g = l & 31, hf = l >> 5;
        int k0 = (j < 2) ? (4*hf + 2*j) : (8 + 4*hf + 2*(j-2));
        const float* wkv = wp.p[2];
        Wu[gid] = h2u(pk2(wkv[k0*64 + g], wkv[(k0+1)*64 + g]));
    } else if (gid < WOTA) {               // WVB: Wv B-frag (wkv cols 32..63)
        int idx = gid - WVB; int l = idx >> 2, j = idx & 3;
        int n = l & 31, hf = l >> 5;
        int k0 = (j < 2) ? (4*hf + 2*j) : (8 + 4*hf + 2*(j-2));
        const float* wkv = wp.p[2];
        Wu[gid] = h2u(pk2(wkv[k0*64 + 32 + n], wkv[(k0+1)*64 + 32 + n]));
    } else if (gid < BQT) {                // WOTA: Wo^T A-frags (2 K-halves)
        int idx = gid - WOTA; int kh = idx >> 8, rem = idx & 255;
        int l = rem >> 2, j = rem & 3;
        int g = l & 31, hf = l >> 5;
        int f0 = kh*16 + ((j < 2) ? (4*hf + 2*j) : (8 + 4*hf + 2*(j-2)));
        const float* wo = wp.p[4];
        Wu[gid] = (g < 16) ? h2u(pk2(wo[f0*16 + g], wo[(f0+1)*16 + g])) : 0u;
    } else if (gid < ILWA) {               // BQT/BKT/BOT f32, Dlay-ordered
        int i = gid - BQT;
        int hf = (i >> 4) & 1, r = i & 15;
        int row = (r & 3) + 8*(r >> 2) + 4*hf;
        float v;
        if      (i < 32) v = wp.p[1][row] * CS2;           // bq * CS/2
        else if (i < 64) v = wp.p[3][row];                 // bk
        else             v = (row < 16) ? wp.p[5][row] : 0.0f;  // bo
        W[gid] = v;
    } else {                               // ILWA: il_w^T A-frags (enc MFMA)
        int idx = gid - ILWA; int s = idx >> 8, rem = idx & 255;
        int l = rem >> 2, j = rem & 3;
        int g = l & 31, hf = l >> 5;
        int k0 = s*16 + ((j < 2) ? (4*hf + 2*j) : (8 + 4*hf + 2*(j-2)));
        const float* ilw = wp.p[8];
        Wu[gid] = h2u(pk2(ilw[k0*32 + g], ilw[(k0+1)*32 + g]));
    }
}

// K1 (MFMA P0-P4): r8-verified structure + r9's aftL 260-pad (bank fix,
// MEASURED: conflicts 16.25M -> 1.57M). launch_bounds RESTORED to (256,3):
// r9's (,4) re-spilled (WRITE 254MB, VGPR squeezed 64, dur 206us) — the
// 128 cap counts the UNIFIED VGPR+AGPR file, and live state (incl. MFMA
// accumulators in AGPRs) exceeds it. (,3)'s ~170 cap is the measured
// no-spill point (r7/r8: WRITE=16MB, 162us). Do not raise to (,4).
__global__ __launch_bounds__(256, 3) void k_main(
    const float* __restrict__ states, const float* __restrict__ hidden,
    const float* W, float* __restrict__ outp)
{
    const u32* Wu = (const u32*)W;

    __shared__ __align__(16) u32   aftL[8][260];     // padded: bank-spread agent rows
    __shared__ __align__(16) float encPartS[4][32][9]; // padded: no 8-way bank conflict
    __shared__ __align__(16) float encS[8][32];
    __shared__ __align__(16) float hnS[8][32];
    __shared__ __align__(16) float membS[8][32];

    const int w    = threadIdx.x >> 6;
    const int lane = threadIdx.x & 63;
    const int sub  = lane >> 5;
    const int t    = lane & 31;      // link row / matrix col
    const int hf   = sub;            // mfma half id
    const int pair = blockIdx.x * 4 + w;
    const int b    = pair >> 5;
    const int a    = ((pair & 31) << 1) | sub;   // tail agent (half-wave)
    const int ba   = b * 64 + a;
    const int ag   = w * 2 + sub;

    float hp = hidden[(size_t)ba * 32 + t];

    // wave-uniform-per-lane weight fragments (QKV)
    f16x8 wqa = mk8(Wu[QTA + lane*4+0], Wu[QTA + lane*4+1], Wu[QTA + lane*4+2], Wu[QTA + lane*4+3]);
    f16x8 wka = mk8(Wu[KTA + lane*4+0], Wu[KTA + lane*4+1], Wu[KTA + lane*4+2], Wu[KTA + lane*4+3]);
    f16x8 wvb = mk8(Wu[WVB + lane*4+0], Wu[WVB + lane*4+1], Wu[WVB + lane*4+2], Wu[WVB + lane*4+3]);
    float bv  = W[BKV + 32 + t];     // V bias per feat = per lane col

    for (int ap = 0; ap < 2; ++ap) {
        const int ag2 = w * 2 + ap;
        const int baA = b * 64 + (((pair & 31) << 1) | ap);
        const float* sp = states + (size_t)baA * 512;
        // S-frag: lane = link t, slots sigma(hf,j) = feats {4hf..+3, 8+4hf..+3}
        float4 f0 = *reinterpret_cast<const float4*>(sp + t*16 + 4*hf);
        float4 f1 = *reinterpret_cast<const float4*>(sp + t*16 + 8 + 4*hf);
        float sv[8] = {f0.x,f0.y,f0.z,f0.w, f1.x,f1.y,f1.z,f1.w};
        f16x8 sf = mk8(h2u(pk2(f0.x,f0.y)), h2u(pk2(f0.z,f0.w)),
                       h2u(pk2(f1.x,f1.y)), h2u(pk2(f1.z,f1.w)));

        // QKV projections (pack each result immediately -> short live ranges)
        f32x16 cc;
        #pragma unroll
        for (int r = 0; r < 16; ++r) cc[r] = W[BQT + hf*16 + r];
        u32 qp[8], kp[8];
        {
            f32x16 dq = MFMA32(wqa, sf, cc);   // Q^T: rows=feat, cols=link
            #pragma unroll
            for (int h = 0; h < 4; ++h) {
                qp[2*h]   = h2u(pk2(dq[4*h],   dq[4*h+1]));
                qp[2*h+1] = h2u(pk2(dq[4*h+2], dq[4*h+3]));
            }
        }
        #pragma unroll
        for (int r = 0; r < 16; ++r) cc[r] = W[BKT + hf*16 + r];
        {
            f32x16 dk = MFMA32(wka, sf, cc);   // K^T
            #pragma unroll
            for (int h = 0; h < 4; ++h) {
                kp[2*h]   = h2u(pk2(dk[4*h],   dk[4*h+1]));
                kp[2*h+1] = h2u(pk2(dk[4*h+2], dk[4*h+3]));
            }
        }
        #pragma unroll
        for (int r = 0; r < 16; ++r) cc[r] = bv;
        f16x8 vaf, vbf;
        {
            f32x16 dv = MFMA32(sf, wvb, cc);   // V: rows=link, cols=feat(lane)
            vaf = mk8(h2u(pk2(dv[0],dv[1])),  h2u(pk2(dv[2],dv[3])),
                      h2u(pk2(dv[4],dv[5])),  h2u(pk2(dv[6],dv[7])));
            vbf = mk8(h2u(pk2(dv[8],dv[9])),  h2u(pk2(dv[10],dv[11])),
                      h2u(pk2(dv[12],dv[13])),h2u(pk2(dv[14],dv[15])));
        }

        f32x16 zro;
        #pragma unroll
        for (int r = 0; r < 16; ++r) zro[r] = 0.0f;

        // per-head attention with out-proj folded in per head-pair
        f32x16 da;
        #pragma unroll
        for (int r = 0; r < 16; ++r) da[r] = W[BOT + hf*16 + r];
        u32 op[4];
        #pragma unroll
        for (int h = 0; h < 4; ++h) {
            // duplicated-head-feat frags (slots j and j+4 carry same feats)
            f16x8 ak = mk8(kp[2*h], kp[2*h+1], kp[2*h], kp[2*h+1]);
            f16x8 bq = mk8(qp[2*h], qp[2*h+1], qp[2*h], qp[2*h+1]);
            f32x16 ds = MFMA32(ak, bq, zro);         // CS-scaled S^T (exp2 dom)
            f32x16 p;
            float ls = 0.0f;
            #pragma unroll
            for (int r = 0; r < 16; ++r) { p[r] = EXP2(ds[r]); ls += p[r]; }
            ls += __shfl_xor(ls, 32, 64);            // full 32-kl row sum
            float inv = 1.0f / ls;                   // deferred to extraction
            f16x8 paf = mk8(h2u(pk2(p[0], p[1])),  h2u(pk2(p[2], p[3])),
                            h2u(pk2(p[4], p[5])),  h2u(pk2(p[6], p[7])));
            f16x8 pbf = mk8(h2u(pk2(p[8], p[9])),  h2u(pk2(p[10],p[11])),
                            h2u(pk2(p[12],p[13])), h2u(pk2(p[14],p[15])));
            f32x16 dt = MFMA32(vaf, paf, zro);
            dt = MFMA32(vbf, pbf, dt);               // O^T_h (unnorm): rows=feat
            // extract valid rows (own regs 4h..4h+3), normalize per lane col q
            op[2*(h&1)]   = h2u(pk2(dt[4*h]*inv,   dt[4*h+1]*inv));
            op[2*(h&1)+1] = h2u(pk2(dt[4*h+2]*inv, dt[4*h+3]*inv));
            if (h & 1) {                             // pair complete -> out-proj
                const int kh = h >> 1;
                f16x8 woh = mk8(Wu[WOTA + kh*256 + lane*4+0], Wu[WOTA + kh*256 + lane*4+1],
                                Wu[WOTA + kh*256 + lane*4+2], Wu[WOTA + kh*256 + lane*4+3]);
                da = MFMA32(woh, mk8(op[0],op[1],op[2],op[3]), da);
            }
        }

        // residual + LN over 16 feats; own regs 0..7 <-> sv feats exactly
        float x[8];
        float sm = 0.0f;
        #pragma unroll
        for (int r = 0; r < 8; ++r) { x[r] = da[r] + sv[r]; sm += x[r]; }
        sm += __shfl_xor(sm, 32, 64);
        float mean = sm * (1.0f / 16.0f);
        float vv = 0.0f;
        #pragma unroll
        for (int r = 0; r < 8; ++r) { float d = x[r] - mean; vv += d * d; }
        vv += __shfl_xor(vv, 32, 64);
        float rs = rsqrtf(vv * (1.0f / 16.0f) + 1e-5f);
        float4 g0 = *reinterpret_cast<const float4*>(W + LN1G + 4*hf);
        float4 g1 = *reinterpret_cast<const float4*>(W + LN1G + 8 + 4*hf);
        float4 e0 = *reinterpret_cast<const float4*>(W + LN1B + 4*hf);
        float4 e1 = *reinterpret_cast<const float4*>(W + LN1B + 8 + 4*hf);
        float gam[8] = {g0.x,g0.y,g0.z,g0.w, g1.x,g1.y,g1.z,g1.w};
        float bet[8] = {e0.x,e0.y,e0.z,e0.w, e1.x,e1.y,e1.z,e1.w};
        float af[8];
        #pragma unroll
        for (int r = 0; r < 8; ++r) af[r] = (x[r] - mean) * rs * gam[r] + bet[r];
        // aft -> LDS flat pair index (link*16+feat)/2 (f16 pairs)
        int i0 = t * 8 + 2 * hf;
        aftL[ag2][i0]     = h2u(pk2(af[0], af[1]));
        aftL[ag2][i0 + 1] = h2u(pk2(af[2], af[3]));
        aftL[ag2][i0 + 4] = h2u(pk2(af[4], af[5]));
        aftL[ag2][i0 + 5] = h2u(pk2(af[6], af[7]));
    }
    __syncthreads();   // all 8 agents' aftL visible block-wide

    // ---- P4 (coop MFMA): enc^T[t][agent] = il_w^T . aft, K split across waves.
    // A = il_w^T frags (ILWA, sigma-packed); B = aft pairs (cols 0..7 = agents,
    // cols 8..31 duplicate agent lane&7 -> broadcast reads, results ignored).
    {
        f32x16 de;
        #pragma unroll
        for (int r = 0; r < 16; ++r) de[r] = 0.0f;
        const int cb = lane & 7;
        #pragma unroll
        for (int ss = 0; ss < 8; ++ss) {
            const int s = w * 8 + ss;    // this wave's K-step (link s)
            uint4 av = *reinterpret_cast<const uint4*>(Wu + ILWA + s*256 + lane*4);
            f16x8 ae = mk8(av.x, av.y, av.z, av.w);
            const u32* ap8 = &aftL[cb][s * 8];
            f16x8 be = mk8(ap8[2*hf], ap8[2*hf + 1], ap8[4 + 2*hf], ap8[5 + 2*hf]);
            de = MFMA32(ae, be, de);     // accumulate over K-steps
        }
        const int c = lane & 31;
        if (c < 8) {
            #pragma unroll
            for (int r = 0; r < 16; ++r)
                encPartS[w][(r & 3) + 8*(r >> 2) + 4*hf][c] = de[r];
        }
    }
    __syncthreads();   // partials from all 4 waves visible
    {
        float enc = W[ILB + t] + encPartS[0][t][ag] + encPartS[1][t][ag]
                  + encPartS[2][t][ag] + encPartS[3][t][ag];
        WB();
        encS[ag][t] = enc;
        WB();
    }

    // ---- P5: GRU ----
    float gi0 = W[BIH + t], gi1 = W[BIH + 32 + t], gi2 = W[BIH + 64 + t];
    float gh0 = W[BHH + t], gh1 = W[BHH + 32 + t], gh2 = W[BHH + 64 + t];
    {
        const float4* eF = (const float4*)&encS[ag][0];
        const float4* hF = (const float4*)(hidden + (size_t)ba * 32);
        const uint4* wi4 = (const uint4*)(Wu + WIHP);
        const uint4* wh4 = (const uint4*)(Wu + WHHP);
        #pragma unroll
        for (int q4 = 0; q4 < 8; ++q4) {
            float4 ev = eF[q4], hv = hF[q4];
            h2 ea = pk2(ev.x, ev.y), eb = pk2(ev.z, ev.w);
            h2 ha = pk2(hv.x, hv.y), hb = pk2(hv.z, hv.w);
            uint4 wiA = wi4[(q4*2)*32 + t], wiB = wi4[(q4*2+1)*32 + t];
            uint4 whA = wh4[(q4*2)*32 + t], whB = wh4[(q4*2+1)*32 + t];
            gi0 = FD(ea, u2h(wiA.x), gi0); gi1 = FD(ea, u2h(wiA.y), gi1); gi2 = FD(ea, u2h(wiA.z), gi2);
            gi0 = FD(eb, u2h(wiB.x), gi0); gi1 = FD(eb, u2h(wiB.y), gi1); gi2 = FD(eb, u2h(wiB.z), gi2);
            gh0 = FD(ha, u2h(whA.x), gh0); gh1 = FD(ha, u2h(whA.y), gh1); gh2 = FD(ha, u2h(whA.z), gh2);
            gh0 = FD(hb, u2h(whB.x), gh0); gh1 = FD(hb, u2h(whB.y), gh1); gh2 = FD(hb, u2h(whB.z), gh2);
        }
    }
    float r  = sigm(gi0 + gh0);
    float z  = sigm(gi1 + gh1);
    float n  = tanhf(gi2 + r * gh2);
    float hn = (1.0f - z) * n + z * hp;
    outp[OUT_H + (size_t)ba * 32 + t] = hn;
    WB();
    hnS[ag][t] = hn;
    WB();

    // ---- P6: memb = relu(h @ ms_w + b); msg = memb @ mg_w[a] + b ----
    {
        const float4* nF = (const float4*)&hnS[ag][0];
        float mb = W[MSB + t];
        #pragma unroll
        for (int q4 = 0; q4 < 8; ++q4) {
            float4 v = nF[q4];
            h2 a2 = pk2(v.x, v.y), b2 = pk2(v.z, v.w);
            mb = FD(a2, u2h(Wu[MSWP + (q4*2)*32 + t]), mb);
            mb = FD(b2, u2h(Wu[MSWP + (q4*2+1)*32 + t]), mb);
        }
        mb = fmaxf(mb, 0.0f);
        WB();
        membS[ag][t] = mb;
        WB();
    }
    {
        const float4* mF = (const float4*)&membS[ag][0];
        float mg = W[MGB + a * 32 + t];
        #pragma unroll
        for (int q4 = 0; q4 < 8; ++q4) {
            float4 v = mF[q4];
            h2 a2 = pk2(v.x, v.y), b2 = pk2(v.z, v.w);
            mg = FD(a2, u2h(Wu[MGWP + a*512 + (q4*2)*32 + t]), mg);
            mg = FD(b2, u2h(Wu[MGWP + a*512 + (q4*2+1)*32 + t]), mg);
        }
        outp[OUT_MM + (size_t)ba * 32 + t] = mg;
    }
}

// K2: per-batch message mean + degenerate comm-attn (unchanged, r5 passing)
__global__ __launch_bounds__(512) void k_mean(const float* W, float* __restrict__ ao_ws,
                                              float* __restrict__ outp)
{
    const int b   = blockIdx.x;
    const int tid = threadIdx.x;
    const int t   = tid & 31;
    const int c   = tid >> 5;        // 0..15
    __shared__ float pS[16][32];
    __shared__ float mmS[32];

    float acc = 0.0f;
    #pragma unroll
    for (int a2 = 0; a2 < 4; ++a2)
        acc += outp[OUT_MM + ((size_t)b * 64 + (a2 * 16 + c)) * 32 + t];
    pS[c][t] = acc;
    __syncthreads();
    if (tid < 32) {
        float ssum = 0.0f;
        #pragma unroll
        for (int cc = 0; cc < 16; ++cc) ssum += pS[cc][t];
        mmS[t] = ssum * (1.0f / 64.0f);
    }
    __syncthreads();
    {
        float mv = mmS[t];
        #pragma unroll
        for (int i = 0; i < 4; ++i)
            outp[OUT_MM + (size_t)b * 2048 + i * 512 + tid] = mv;
    }
    if (tid < 32) {
        float v = W[MABKVV + t];
        #pragma unroll 8
        for (int k = 0; k < 32; ++k) v += mmS[k] * W[MAWKVV + k * 32 + t];
        float o = W[MABO + t];
        #pragma unroll 8
        for (int k = 0; k < 32; ++k) o += __shfl(v, k, 64) * W[MAWO + k * 32 + t];
        ao_ws[b * 32 + t] = o;
    }
}

// K3: LN2(h + ao[b]) -> feat=[h,after] -> relu(qs) -> per-agent Q head
// (unchanged, r5 passing)
__global__ __launch_bounds__(512) void k_tail(
    const float* __restrict__ ao_ws, const float* W, float* __restrict__ outp)
{
    const u32* Wu = (const u32*)W;
    __shared__ __align__(16) float featS[16][64];
    __shared__ __align__(16) float qeS[16][32];
    const int w    = threadIdx.x >> 6;
    const int lane = threadIdx.x & 63;
    const int sub  = lane >> 5;
    const int t    = lane & 31;
    const int ag   = w * 2 + sub;
    const int pair = blockIdx.x * 8 + w;
    const int b    = pair >> 5;
    const int a    = ((pair & 31) << 1) | sub;
    const int ba   = b * 64 + a;

    float h  = outp[OUT_H + (size_t)ba * 32 + t];
    float ao = ao_ws[b * 32 + t];
    float x  = h + ao;
    float sm = x;
    #pragma unroll
    for (int m2 = 1; m2 < 32; m2 <<= 1) sm += __shfl_xor(sm, m2, 64);
    float mean = sm * (1.0f / 32.0f);
    float dx = x - mean;
    float vv = dx * dx;
    #pragma unroll
    for (int m2 = 1; m2 < 32; m2 <<= 1) vv += __shfl_xor(vv, m2, 64);
    float var   = vv * (1.0f / 32.0f);
    float after = dx * rsqrtf(var + 1e-5f) * W[LN2G + t] + W[LN2B + t];

    featS[ag][t]      = h;
    featS[ag][32 + t] = after;
    WB();
    {
        const float4* fF = (const float4*)&featS[ag][0];
        float acc = W[QSB + t];
        #pragma unroll
        for (int q4 = 0; q4 < 16; ++q4) {
            float4 v = fF[q4];
            h2 a2 = pk2(v.x, v.y), b2 = pk2(v.z, v.w);
            acc = FD(a2, u2h(Wu[QSWP + (q4*2)*32 + t]), acc);
            acc = FD(b2, u2h(Wu[QSWP + (q4*2+1)*32 + t]), acc);
        }
        acc = fmaxf(acc, 0.0f);
        WB();
        qeS[ag][t] = acc;
        WB();
    }
    if (t < 16) {
        const float4* qF = (const float4*)&qeS[ag][0];
        float qa = W[AHB + a * 16 + t];
        #pragma unroll
        for (int q4 = 0; q4 < 8; ++q4) {
            float4 v = qF[q4];
            h2 a2 = pk2(v.x, v.y), b2 = pk2(v.z, v.w);
            qa = FD(a2, u2h(Wu[AHWP + a*256 + (q4*2)*16 + t]), qa);
            qa = FD(b2, u2h(Wu[AHWP + a*256 + (q4*2+1)*16 + t]), qa);
        }
        outp[OUT_Q + (size_t)ba * 16 + t] = qa;
    }
}

extern "C" void kernel_launch(void* const* d_in, const int* in_sizes, int n_in,
                              void* d_out, int out_size, void* d_ws, size_t ws_size,
                              hipStream_t stream) {
    (void)in_sizes; (void)n_in; (void)out_size; (void)ws_size;
    WP wp;
    for (int i = 0; i < 30; ++i) wp.p[i] = (const float*)d_in[i + 2];

    float* W     = (float*)d_ws;
    float* ao_ws = W + W_ALLOC;   // 1024*32 f32

    const float* states = (const float*)d_in[0];
    const float* hidden = (const float*)d_in[1];
    float* outp = (float*)d_out;

    kw_conv<<<dim3((W_TOTAL3 + 255) / 256), dim3(256), 0, stream>>>(wp, W);
    k_main<<<dim3(8192), dim3(256), 0, stream>>>(states, hidden, W, outp);
    k_mean<<<dim3(1024), dim3(512), 0, stream>>>(W, ao_ws, outp);
    k_tail<<<dim3(4096), dim3(512), 0, stream>>>(ao_ws, W, outp);
}